// Round 1
// baseline (682.296 us; speedup 1.0000x reference)
//
#include <hip/hip_runtime.h>

#define DD     1024
#define HH     16
#define KVH    4
#define HDIM   64
#define NLAYER 6
#define FDIM   4096
#define VDIM   4096
#define NCODE  15
#define SS     16
#define KVDIM  256      // KVH*HDIM
#define EPSF   1e-6f

__device__ __forceinline__ float dot4(float4 a, float4 b){
  return a.x*b.x + a.y*b.y + a.z*b.z + a.w*b.w;
}
__device__ __forceinline__ float wave_sum(float v){
  #pragma unroll
  for (int o=32;o;o>>=1) v += __shfl_xor(v,o);
  return v;
}
__device__ __forceinline__ float grp16_sum(float v){
  #pragma unroll
  for (int o=8;o;o>>=1) v += __shfl_xor(v,o);
  return v;
}
__device__ __forceinline__ float grp16_max(float v){
  #pragma unroll
  for (int o=8;o;o>>=1) v = fmaxf(v, __shfl_xor(v,o));
  return v;
}

// copy input embeds -> hidden workspace
__global__ __launch_bounds__(256) void k_init(const float* __restrict__ emb,
                                              float* __restrict__ hidden){
  ((float4*)hidden)[threadIdx.x] = ((const float4*)emb)[threadIdx.x];
}

// fused rms(ln1) + QKV matvec. grid=384 blocks x 256 thr (wave per row, 1536 rows)
__global__ __launch_bounds__(256) void k_qkv(
    const float* __restrict__ Wq, const float* __restrict__ Wk, const float* __restrict__ Wv,
    const float* __restrict__ hidden, const float* __restrict__ ln,
    float* __restrict__ out /*1536: q(1024),k(256),v(256)*/)
{
  __shared__ float xs[DD];
  __shared__ float red[4];
  const int t = threadIdx.x, lane = t & 63, wid = t >> 6;
  float4 hv = ((const float4*)hidden)[t];
  float ss = wave_sum(dot4(hv,hv));
  if (lane==0) red[wid] = ss;
  __syncthreads();
  const float inv = rsqrtf((red[0]+red[1]+red[2]+red[3])*(1.0f/DD) + EPSF);
  float4 lw = ((const float4*)ln)[t];
  float4 xv; xv.x=hv.x*inv*lw.x; xv.y=hv.y*inv*lw.y; xv.z=hv.z*inv*lw.z; xv.w=hv.w*inv*lw.w;
  ((float4*)xs)[t] = xv;
  __syncthreads();
  const int row = blockIdx.x*4 + wid;
  const float* Wrow;
  if (row < 1024)      Wrow = Wq + (size_t)row*DD;
  else if (row < 1280) Wrow = Wk + (size_t)(row-1024)*DD;
  else                 Wrow = Wv + (size_t)(row-1280)*DD;
  const float4* w4 = (const float4*)Wrow;
  const float4* x4 = (const float4*)xs;
  float acc = 0.f;
  #pragma unroll
  for (int j=0;j<4;j++) acc += dot4(w4[j*64+lane], x4[j*64+lane]);
  acc = wave_sum(acc);
  if (lane==0) out[row] = acc;
}

// single block: q/k rms+rope, cache merge, softmax attention -> ao; emits knew/vnew
__global__ __launch_bounds__(256) void k_attn(
    const float* __restrict__ qbuf, const float* __restrict__ kbuf, const float* __restrict__ vbuf,
    const float* __restrict__ qn, const float* __restrict__ kn,
    const float* __restrict__ inv_freq, const int* __restrict__ cache_len,
    const float* __restrict__ kcache_l, const float* __restrict__ vcache_l,
    const float* __restrict__ pmask, const float* __restrict__ umask,
    float* __restrict__ ao, float* __restrict__ knew, float* __restrict__ vnew)
{
  __shared__ float qsh[DD];
  __shared__ float ksh[KVDIM];
  __shared__ float vsh[KVDIM];
  __shared__ float awsh[HH*SS];
  __shared__ float umsh[SS], pmsh[SS];
  const int t = threadIdx.x;
  if (t < SS){ umsh[t]=umask[t]; pmsh[t]=pmask[t]; }
  const float pos = (float)cache_len[0];

  // ---- q: per-head rms + rope (16 heads x 16 threads, 4 elems/thread) ----
  {
    const int idx16 = t & 15;
    float4 q = ((const float4*)qbuf)[t];
    float ss = grp16_sum(dot4(q,q));
    const float inv = rsqrtf(ss*(1.0f/HDIM)+EPSF);
    float4 w = ((const float4*)qn)[idx16];
    float x0=q.x*inv*w.x, x1=q.y*inv*w.y, x2=q.z*inv*w.z, x3=q.w*inv*w.w;
    float p0=__shfl_xor(x0,8), p1=__shfl_xor(x1,8), p2=__shfl_xor(x2,8), p3=__shfl_xor(x3,8);
    const int d0 = idx16*4;
    const bool lolane = (idx16 < 8);
    const int m = lolane ? d0 : d0-32;
    const float f0=inv_freq[m]*pos, f1=inv_freq[m+1]*pos, f2=inv_freq[m+2]*pos, f3=inv_freq[m+3]*pos;
    const float sgn = lolane ? -1.f : 1.f;
    float4 r;
    r.x = x0*cosf(f0) + sgn*p0*sinf(f0);
    r.y = x1*cosf(f1) + sgn*p1*sinf(f1);
    r.z = x2*cosf(f2) + sgn*p2*sinf(f2);
    r.w = x3*cosf(f3) + sgn*p3*sinf(f3);
    ((float4*)qsh)[t] = r;
  }
  // ---- k: per-head rms + rope (wave 0 only), v passthrough ----
  if (t < 64){
    const int idx16 = t & 15;
    float4 k = ((const float4*)kbuf)[t];
    float ss = grp16_sum(dot4(k,k));
    const float inv = rsqrtf(ss*(1.0f/HDIM)+EPSF);
    float4 w = ((const float4*)kn)[idx16];
    float x0=k.x*inv*w.x, x1=k.y*inv*w.y, x2=k.z*inv*w.z, x3=k.w*inv*w.w;
    float p0=__shfl_xor(x0,8), p1=__shfl_xor(x1,8), p2=__shfl_xor(x2,8), p3=__shfl_xor(x3,8);
    const int d0 = idx16*4;
    const bool lolane = (idx16 < 8);
    const int m = lolane ? d0 : d0-32;
    const float f0=inv_freq[m]*pos, f1=inv_freq[m+1]*pos, f2=inv_freq[m+2]*pos, f3=inv_freq[m+3]*pos;
    const float sgn = lolane ? -1.f : 1.f;
    float4 r;
    r.x = x0*cosf(f0) + sgn*p0*sinf(f0);
    r.y = x1*cosf(f1) + sgn*p1*sinf(f1);
    r.z = x2*cosf(f2) + sgn*p2*sinf(f2);
    r.w = x3*cosf(f3) + sgn*p3*sinf(f3);
    ((float4*)ksh)[t] = r;
    ((float4*)knew)[t] = r;
    float4 v = ((const float4*)vbuf)[t];
    ((float4*)vsh)[t] = v;
    ((float4*)vnew)[t] = v;
  }
  __syncthreads();
  // ---- scores + softmax: thread = (head h, pos s) ----
  {
    const int h = t>>4, s = t&15, kvh = h>>2;
    const float um = umsh[s], pm = pmsh[s];
    const float* kcol = kcache_l + (size_t)(kvh*HDIM)*SS + s;
    const float* ksrc = ksh + kvh*HDIM;
    const float* qv   = qsh + h*HDIM;
    float dot = 0.f;
    #pragma unroll
    for (int d=0; d<HDIM; d++){
      float kc = kcol[d*SS]*(1.f-um) + ksrc[d]*um;
      dot += qv[d]*kc;
    }
    const float sc = dot*0.125f + pm;   // scale = 1/sqrt(64)
    const float mx = grp16_max(sc);
    const float e  = expf(sc-mx);
    const float sm = grp16_sum(e);
    awsh[t] = e/sm;
  }
  __syncthreads();
  // ---- ao[h][d] = sum_s aw * vc ----
  {
    const int h = t>>4, idx16 = t&15, kvh = h>>2;
    const int cb = kvh*HDIM + idx16*4;
    float a0=0,a1=0,a2=0,a3=0;
    #pragma unroll
    for (int s=0;s<SS;s++){
      const float aw = awsh[h*16+s];
      const float um = umsh[s];
      a0 += aw*(vcache_l[(size_t)(cb+0)*SS+s]*(1.f-um)+vsh[cb+0]*um);
      a1 += aw*(vcache_l[(size_t)(cb+1)*SS+s]*(1.f-um)+vsh[cb+1]*um);
      a2 += aw*(vcache_l[(size_t)(cb+2)*SS+s]*(1.f-um)+vsh[cb+2]*um);
      a3 += aw*(vcache_l[(size_t)(cb+3)*SS+s]*(1.f-um)+vsh[cb+3]*um);
    }
    ((float4*)ao)[t] = make_float4(a0,a1,a2,a3);
  }
}

// Wo matvec + residual. grid=256
__global__ __launch_bounds__(256) void k_o(
    const float* __restrict__ Wo, const float* __restrict__ ao, float* __restrict__ hidden)
{
  __shared__ float xs[DD];
  const int t=threadIdx.x, lane=t&63, wid=t>>6;
  ((float4*)xs)[t] = ((const float4*)ao)[t];
  __syncthreads();
  const int row = blockIdx.x*4 + wid;
  const float4* w4 = (const float4*)(Wo + (size_t)row*DD);
  const float4* x4 = (const float4*)xs;
  float acc=0.f;
  #pragma unroll
  for (int j=0;j<4;j++) acc += dot4(w4[j*64+lane], x4[j*64+lane]);
  acc = wave_sum(acc);
  if (lane==0) hidden[row] += acc;
}

// fused rms(ln2) + gate/up matvec + silu*mul. grid=1024 (wave computes both dots for a row)
__global__ __launch_bounds__(256) void k_gu(
    const float* __restrict__ Wg, const float* __restrict__ Wu,
    const float* __restrict__ hidden, const float* __restrict__ ln,
    float* __restrict__ act)
{
  __shared__ float xs[DD];
  __shared__ float red[4];
  const int t=threadIdx.x, lane=t&63, wid=t>>6;
  float4 hv = ((const float4*)hidden)[t];
  float ss = wave_sum(dot4(hv,hv));
  if (lane==0) red[wid]=ss;
  __syncthreads();
  const float inv = rsqrtf((red[0]+red[1]+red[2]+red[3])*(1.0f/DD) + EPSF);
  float4 lw = ((const float4*)ln)[t];
  float4 xv; xv.x=hv.x*inv*lw.x; xv.y=hv.y*inv*lw.y; xv.z=hv.z*inv*lw.z; xv.w=hv.w*inv*lw.w;
  ((float4*)xs)[t] = xv;
  __syncthreads();
  const int row = blockIdx.x*4 + wid;       // 0..4095
  const float4* g4 = (const float4*)(Wg + (size_t)row*DD);
  const float4* u4 = (const float4*)(Wu + (size_t)row*DD);
  const float4* x4 = (const float4*)xs;
  float ag=0.f, au=0.f;
  #pragma unroll
  for (int j=0;j<4;j++){
    float4 x = x4[j*64+lane];
    ag += dot4(g4[j*64+lane], x);
    au += dot4(u4[j*64+lane], x);
  }
  ag = wave_sum(ag); au = wave_sum(au);
  if (lane==0){
    float sg = ag/(1.f+expf(-ag));        // silu
    act[row] = sg*au;
  }
}

// Wdown matvec (K=4096) + residual. grid=256
__global__ __launch_bounds__(256) void k_down(
    const float* __restrict__ Wd, const float* __restrict__ act, float* __restrict__ hidden)
{
  __shared__ float xs[FDIM];
  const int t=threadIdx.x, lane=t&63, wid=t>>6;
  #pragma unroll
  for (int j=0;j<4;j++) ((float4*)xs)[j*256+t] = ((const float4*)act)[j*256+t];
  __syncthreads();
  const int row = blockIdx.x*4 + wid;
  const float4* w4 = (const float4*)(Wd + (size_t)row*FDIM);
  const float4* x4 = (const float4*)xs;
  float acc=0.f;
  #pragma unroll
  for (int j=0;j<16;j++) acc += dot4(w4[j*64+lane], x4[j*64+lane]);
  acc = wave_sum(acc);
  if (lane==0) hidden[row] += acc;
}

// block0: final rms -> normed ws + hidden_out; blocks 1..192: nkc/nvc assembly
__global__ __launch_bounds__(256) void k_finalize(
    const float* __restrict__ hidden, const float* __restrict__ norm_w,
    const float* __restrict__ kcache, const float* __restrict__ vcache,
    const float* __restrict__ knew, const float* __restrict__ vnew,
    const float* __restrict__ umask,
    float* __restrict__ normed, float* __restrict__ out_hidden,
    float* __restrict__ out_nkc, float* __restrict__ out_nvc)
{
  if (blockIdx.x == 0){
    __shared__ float red[4];
    const int t=threadIdx.x, lane=t&63, wid=t>>6;
    float4 hv = ((const float4*)hidden)[t];
    float ss = wave_sum(dot4(hv,hv));
    if (lane==0) red[wid]=ss;
    __syncthreads();
    const float inv = rsqrtf((red[0]+red[1]+red[2]+red[3])*(1.0f/DD) + EPSF);
    float4 w = ((const float4*)norm_w)[t];
    float4 nv; nv.x=hv.x*inv*w.x; nv.y=hv.y*inv*w.y; nv.z=hv.z*inv*w.z; nv.w=hv.w*inv*w.w;
    ((float4*)normed)[t]   = nv;
    ((float4*)out_hidden)[t] = nv;
  } else {
    const int j = (blockIdx.x-1)*256 + threadIdx.x;   // 0..49151
    if (j < NLAYER*KVDIM*SS){
      const int s = j & 15, c = j >> 4;
      const float um = umask[s];
      out_nkc[j] = kcache[j]*(1.f-um) + knew[c]*um;
    } else {
      const int i = j - NLAYER*KVDIM*SS;
      const int s = i & 15, c = i >> 4;
      const float um = umask[s];
      out_nvc[i] = vcache[i]*(1.f-um) + vnew[c]*um;
    }
  }
}

// lm_head: 61440 rows x 1024. grid=15360
__global__ __launch_bounds__(256) void k_lmhead(
    const float* __restrict__ W, const float* __restrict__ normed, float* __restrict__ out)
{
  __shared__ float xs[DD];
  const int t=threadIdx.x, lane=t&63, wid=t>>6;
  ((float4*)xs)[t] = ((const float4*)normed)[t];
  __syncthreads();
  const int row = blockIdx.x*4 + wid;
  const float4* w4 = (const float4*)(W + (size_t)row*DD);
  const float4* x4 = (const float4*)xs;
  float acc=0.f;
  #pragma unroll
  for (int j=0;j<4;j++) acc += dot4(w4[j*64+lane], x4[j*64+lane]);
  acc = wave_sum(acc);
  if (lane==0) out[row] = acc;
}

extern "C" void kernel_launch(void* const* d_in, const int* in_sizes, int n_in,
                              void* d_out, int out_size, void* d_ws, size_t ws_size,
                              hipStream_t stream)
{
  const float* emb    = (const float*)d_in[0];
  const int*   clen   = (const int*)  d_in[1];
  const float* kcache = (const float*)d_in[2];
  const float* pmask  = (const float*)d_in[3];
  const float* umask  = (const float*)d_in[4];
  const float* vcache = (const float*)d_in[5];
  const float* invf   = (const float*)d_in[6];
  const float* Wq     = (const float*)d_in[7];
  const float* Wk     = (const float*)d_in[8];
  const float* Wv     = (const float*)d_in[9];
  const float* Wo     = (const float*)d_in[10];
  const float* ln1    = (const float*)d_in[11];
  const float* ln2    = (const float*)d_in[12];
  const float* qn     = (const float*)d_in[13];
  const float* kn     = (const float*)d_in[14];
  const float* Wg     = (const float*)d_in[15];
  const float* Wu     = (const float*)d_in[16];
  const float* Wd     = (const float*)d_in[17];
  const float* nw     = (const float*)d_in[18];
  const float* lmw    = (const float*)d_in[19];
  float* out = (float*)d_out;
  float* ws  = (float*)d_ws;

  float* hidden = ws;            // 1024
  float* qkv    = ws + 1024;     // 1536
  float* ao     = ws + 2560;     // 1024
  float* act    = ws + 3584;     // 4096
  float* knew   = ws + 7680;     // 1536
  float* vnew   = ws + 9216;     // 1536
  float* normed = ws + 10752;    // 1024

  // d_out layout: logits(61440) | hidden_out(1024) | nkc(24576) | nvc(24576)
  float* out_logits = out;
  float* out_hidden = out + NCODE*VDIM;
  float* out_nkc    = out_hidden + DD;
  float* out_nvc    = out_nkc + NLAYER*KVDIM*SS;

  k_init<<<1,256,0,stream>>>(emb, hidden);
  for (int l=0; l<NLAYER; l++){
    k_qkv<<<384,256,0,stream>>>(Wq + (size_t)l*HH*HDIM*DD, Wk + (size_t)l*KVDIM*DD,
                                Wv + (size_t)l*KVDIM*DD, hidden, ln1 + l*DD, qkv);
    k_attn<<<1,256,0,stream>>>(qkv, qkv+1024, qkv+1280, qn + l*HDIM, kn + l*HDIM,
                               invf, clen,
                               kcache + (size_t)l*KVDIM*SS, vcache + (size_t)l*KVDIM*SS,
                               pmask, umask, ao, knew + l*KVDIM, vnew + l*KVDIM);
    k_o<<<256,256,0,stream>>>(Wo + (size_t)l*DD*HH*HDIM, ao, hidden);
    k_gu<<<1024,256,0,stream>>>(Wg + (size_t)l*FDIM*DD, Wu + (size_t)l*FDIM*DD,
                                hidden, ln2 + l*DD, act);
    k_down<<<256,256,0,stream>>>(Wd + (size_t)l*DD*FDIM, act, hidden);
  }
  k_finalize<<<193,256,0,stream>>>(hidden, nw, kcache, vcache, knew, vnew, umask,
                                   normed, out_hidden, out_nkc, out_nvc);
  k_lmhead<<<15360,256,0,stream>>>(lmw, normed, out_logits);
}